// Round 8
// baseline (314.777 us; speedup 1.0000x reference)
//
#include <hip/hip_runtime.h>
#include <hip/hip_bf16.h>

// ---------------------------------------------------------------------------
// GraphSAGE forward, bf16 MFMA GEMMs (128x128, BK=32, 3-buffer depth-2
// counted-vmcnt pipeline) + CSR gather aggregation.
//   xb  = bf16(x)                               (one streaming pass)
//   Wc  = bf16(W_pre2 @ W_pre), bc = W_pre2 @ b_pre + b_pre2
//   Acat[M,512] bf16: cols 0..255 = mean1, cols 256..511 = H2 (later TR)
//   H2  = xb @ Wc.T + bc
//   mean1[n] = mean_{s in N(n)} H2[s]
//   H3  = relu(Acat @ [Wl1|Wr1].T + bl1)        (single K=512 MFMA GEMM)
//   TR  = H3 @ [Wl2;Wr2].T  -> overwrites Acat cols 256..511
//   out = l2norm(mean_s(T[s]) + bl2 + R)
// GEMM K-loop (T4): prologue issues S0,S1; per iter:
//   s_waitcnt vmcnt(4)   <- S(t) landed, S(t+1)'s 4 loads STAY IN FLIGHT
//   s_barrier            <- raw barrier, no drain
//   issue S(t+2) -> buf[(t+2)%3]   (freed by compute(t-1), safe past barrier)
//   compute(t) from buf[t%3]
// R2..R6 all drained vmcnt(0) at every step (__syncthreads) -> depth-0
// pipeline -> 75us regardless of structure. Counted vmcnt is the lever.
// ---------------------------------------------------------------------------

typedef __attribute__((ext_vector_type(4))) float f32x4;
typedef __attribute__((ext_vector_type(8))) short s8v;

__device__ __forceinline__ float bf2f(unsigned short u) {
  union { unsigned int i; float f; } v; v.i = ((unsigned int)u) << 16; return v.f;
}
__device__ __forceinline__ unsigned short f2bf(float f) {
  unsigned int u = __builtin_bit_cast(unsigned int, f);
  u += 0x7fffu + ((u >> 16) & 1u);          // round-to-nearest-even
  return (unsigned short)(u >> 16);
}

// ------------------------------ CSR build ----------------------------------
__global__ __launch_bounds__(256) void zero_int_kernel(int* __restrict__ p, int n) {
  int i = blockIdx.x * blockDim.x + threadIdx.x;
  const int stride = gridDim.x * blockDim.x;
  for (; i < n; i += stride) p[i] = 0;
}

__global__ __launch_bounds__(256) void count_kernel(const int* __restrict__ dst,
                                                    int* __restrict__ cnt, int E) {
  const int e = blockIdx.x * blockDim.x + threadIdx.x;
  if (e < E) atomicAdd(&cnt[dst[e]], 1);
}

__global__ __launch_bounds__(256) void scan_pass1(const int* __restrict__ cnt,
                                                  int* __restrict__ bsum, int M) {
  __shared__ int red[256];
  const int t = threadIdx.x;
  const int i = blockIdx.x * 256 + t;
  red[t] = (i < M) ? cnt[i] : 0;
  __syncthreads();
  for (int off = 128; off > 0; off >>= 1) {
    if (t < off) red[t] += red[t + off];
    __syncthreads();
  }
  if (t == 0) bsum[blockIdx.x] = red[0];
}

__global__ __launch_bounds__(256) void scan_pass2(const int* __restrict__ bsum,
    int* __restrict__ boff, int* __restrict__ rowptr, int nb, int M, int E) {
  __shared__ int buf[256];
  const int t = threadIdx.x;
  const int v = (t < nb) ? bsum[t] : 0;
  buf[t] = v;
  __syncthreads();
  for (int off = 1; off < 256; off <<= 1) {
    const int add = (t >= off) ? buf[t - off] : 0;
    __syncthreads();
    buf[t] += add;
    __syncthreads();
  }
  if (t < nb) boff[t] = buf[t] - v;
  if (t == 0) rowptr[M] = E;
}

__global__ __launch_bounds__(256) void scan_pass3(int* __restrict__ cnt,
    const int* __restrict__ boff, int* __restrict__ rowptr, int M) {
  __shared__ int buf[256];
  const int t = threadIdx.x;
  const int i = blockIdx.x * 256 + t;
  const int v = (i < M) ? cnt[i] : 0;
  buf[t] = v;
  __syncthreads();
  for (int off = 1; off < 256; off <<= 1) {
    const int add = (t >= off) ? buf[t - off] : 0;
    __syncthreads();
    buf[t] += add;
    __syncthreads();
  }
  if (i < M) {
    rowptr[i] = buf[t] - v + boff[blockIdx.x];
    cnt[i] = 0;   // reset for fill cursor
  }
}

__global__ __launch_bounds__(256) void fill_kernel(const int* __restrict__ src,
    const int* __restrict__ dst, const int* __restrict__ rowptr,
    int* __restrict__ cursor, unsigned short* __restrict__ eidx, int E) {
  const int e = blockIdx.x * blockDim.x + threadIdx.x;
  if (e >= E) return;
  const int d = dst[e];
  const int pos = rowptr[d] + atomicAdd(&cursor[d], 1);
  eidx[pos] = (unsigned short)src[e];
}

// ---------------------- x -> bf16 streaming convert ------------------------
__global__ __launch_bounds__(256) void cvt_x_kernel(const float* __restrict__ x,
    unsigned short* __restrict__ xb, int n) {   // n = M*512, multiple of 8
  int i = (blockIdx.x * 256 + threadIdx.x) * 8;
  const int stride = gridDim.x * 256 * 8;
  for (; i < n; i += stride) {
    const float4 f0 = *(const float4*)(x + i);
    const float4 f1 = *(const float4*)(x + i + 4);
    s8v p;
    p[0] = (short)f2bf(f0.x); p[1] = (short)f2bf(f0.y);
    p[2] = (short)f2bf(f0.z); p[3] = (short)f2bf(f0.w);
    p[4] = (short)f2bf(f1.x); p[5] = (short)f2bf(f1.y);
    p[6] = (short)f2bf(f1.z); p[7] = (short)f2bf(f1.w);
    *(s8v*)(xb + i) = p;
  }
}

// --------------------- fused weight preparation ----------------------------
// blocks 0..255: Wc row o ; block 256: bc ; 257..768: Bc1 ; 769..1024: Bc2
__global__ __launch_bounds__(256) void prep_kernel(const float* __restrict__ Wp,
    const float* __restrict__ Wp2, const float* __restrict__ bp,
    const float* __restrict__ bp2, const float* __restrict__ Wl1,
    const float* __restrict__ Wr1, const float* __restrict__ Wl2,
    const float* __restrict__ Wr2, unsigned short* __restrict__ Wc,
    float* __restrict__ bc, unsigned short* __restrict__ Bc1,
    unsigned short* __restrict__ Bc2) {
  const int b = blockIdx.x, t = threadIdx.x;
  if (b < 256) {
    __shared__ float wrow[256];
    wrow[t] = Wp2[b * 256 + t];
    __syncthreads();
    float a0 = 0.f, a1 = 0.f;
    for (int m = 0; m < 256; ++m) {
      const float w = wrow[m];
      a0 = fmaf(w, Wp[m * 512 + t], a0);
      a1 = fmaf(w, Wp[m * 512 + 256 + t], a1);
    }
    Wc[b * 512 + t] = f2bf(a0);
    Wc[b * 512 + 256 + t] = f2bf(a1);
  } else if (b == 256) {
    float s = 0.f;
    for (int m = 0; m < 256; ++m) s = fmaf(Wp2[t * 256 + m], bp[m], s);
    bc[t] = s + bp2[t];
  } else if (b < 769) {
    const int idx = (b - 257) * 256 + t;   // < 256*512
    const int o = idx >> 9, k = idx & 511;
    const float v = (k < 256) ? Wl1[o * 256 + k] : Wr1[o * 256 + (k - 256)];
    Bc1[idx] = f2bf(v);
  } else {
    const int idx = (b - 769) * 256 + t;   // < 256*256
    const int r = idx >> 8, k = idx & 255;
    const float v = (r < 128) ? Wl2[r * 256 + k] : Wr2[(r - 128) * 256 + k];
    Bc2[idx] = f2bf(v);
  }
}

// ---------------------------------------------------------------------------
// MFMA GEMM: C[M,256] = act(A[M,K] @ B[256,K].T + bias), bf16 in, fp32 acc.
// ---------------------------------------------------------------------------
template <int K, int ASTRIDE, int CSTRIDE, int CBASE, bool BIAS_EN, bool RELU_EN>
__global__ __launch_bounds__(256) void mfma_gemm(
    const unsigned short* __restrict__ Ap, const unsigned short* __restrict__ Bp,
    const float* __restrict__ bias, unsigned short* __restrict__ Cp, int M, int nwg) {
  constexpr int NT = K / 32;
  constexpr int BUF = 16384;           // As 8KB | Bs 8KB per buffer
  __shared__ __align__(16) char smem[3 * BUF];

  // bijective XCD chunking (m204); pair (wg, wg^1) shares A rows on one XCD
  const int xcd = blockIdx.x & 7, bidx = blockIdx.x >> 3;
  const int q = nwg >> 3, r = nwg & 7;
  const int wg = (xcd < r ? xcd * (q + 1) : r * (q + 1) + (xcd - r) * q) + bidx;
  const int bm = (wg >> 1) * 128;
  const int bn = (wg & 1) * 128;

  const int t = threadIdx.x, w = t >> 6, l = t & 63;
  const int wr = (w >> 1) * 64, wc = (w & 1) * 64;
  const int lane15 = l & 15, half = l >> 4;     // half = k-chunk 0..3

  // staging map: thread t covers LDS rows sr (j=0) and 64+sr (j=1),
  // phys slot sp; swizzle slot = sp ^ ((row>>1)&3) (R2/R6-verified: 0 confl.)
  const int sr = t >> 2, sp = t & 3;
  const int ar0 = min(bm + sr, M - 1);
  const int ar1 = min(bm + 64 + sr, M - 1);
  const int sl0 = sp ^ ((sr >> 1) & 3);
  const int sl1 = sp ^ (((64 + sr) >> 1) & 3);
  const unsigned short* apb0 = Ap + (size_t)ar0 * ASTRIDE + sl0 * 8;
  const unsigned short* apb1 = Ap + (size_t)ar1 * ASTRIDE + sl1 * 8;
  const unsigned short* bpb0 = Bp + (size_t)(bn + sr) * K + sl0 * 8;
  const unsigned short* bpb1 = Bp + (size_t)(bn + 64 + sr) * K + sl1 * 8;

  f32x4 acc[4][4];
#pragma unroll
  for (int i = 0; i < 4; ++i)
#pragma unroll
    for (int j = 0; j < 4; ++j) acc[i][j] = f32x4{0.f, 0.f, 0.f, 0.f};

  auto stage = [&](int bufOff, int k0) {   // 4 global_load_lds per thread
    __builtin_amdgcn_global_load_lds((const unsigned int*)(apb0 + k0),
        (unsigned int*)(smem + bufOff + w * 1024), 16, 0, 0);
    __builtin_amdgcn_global_load_lds((const unsigned int*)(apb1 + k0),
        (unsigned int*)(smem + bufOff + 4096 + w * 1024), 16, 0, 0);
    __builtin_amdgcn_global_load_lds((const unsigned int*)(bpb0 + k0),
        (unsigned int*)(smem + bufOff + 8192 + w * 1024), 16, 0, 0);
    __builtin_amdgcn_global_load_lds((const unsigned int*)(bpb1 + k0),
        (unsigned int*)(smem + bufOff + 12288 + w * 1024), 16, 0, 0);
  };
  auto compute = [&](int bufOff) {
    const char* Ab = smem + bufOff;
    const char* Bb = Ab + 8192;
    s8v af[4], bv[4];
#pragma unroll
    for (int ms = 0; ms < 4; ++ms) {
      const int rr = wr + ms * 16 + lane15;
      af[ms] = *(const s8v*)(Ab + rr * 64 + ((half ^ ((rr >> 1) & 3)) << 4));
    }
#pragma unroll
    for (int ns = 0; ns < 4; ++ns) {
      const int rr = wc + ns * 16 + lane15;
      bv[ns] = *(const s8v*)(Bb + rr * 64 + ((half ^ ((rr >> 1) & 3)) << 4));
    }
#pragma unroll
    for (int ms = 0; ms < 4; ++ms)
#pragma unroll
      for (int ns = 0; ns < 4; ++ns)
        acc[ms][ns] =
            __builtin_amdgcn_mfma_f32_16x16x32_bf16(af[ms], bv[ns], acc[ms][ns], 0, 0, 0);
  };

  // --- prologue: two tiles in flight ---
  stage(0, 0);
  stage(BUF, 32);

  int offC = 0, offI = 2 * BUF;
#pragma unroll 1
  for (int tt = 0; tt < NT - 1; ++tt) {
    // S(tt) landed; S(tt+1)'s 4 loads remain in flight across the barrier
    asm volatile("s_waitcnt vmcnt(4)" ::: "memory");
    __builtin_amdgcn_sched_barrier(0);
    __builtin_amdgcn_s_barrier();
    if (tt + 2 < NT) stage(offI, (tt + 2) * 32);
    compute(offC);
    offC = (offC == 2 * BUF) ? 0 : offC + BUF;
    offI = (offI == 2 * BUF) ? 0 : offI + BUF;
  }
  asm volatile("s_waitcnt vmcnt(0)" ::: "memory");
  __builtin_amdgcn_sched_barrier(0);
  __builtin_amdgcn_s_barrier();
  compute(offC);

  // --- epilogue ---
  float bias_l[4];
  if (BIAS_EN) {
#pragma unroll
    for (int ns = 0; ns < 4; ++ns) bias_l[ns] = bias[bn + wc + ns * 16 + lane15];
  }
#pragma unroll
  for (int ms = 0; ms < 4; ++ms)
#pragma unroll
    for (int ns = 0; ns < 4; ++ns) {
      const int col = bn + wc + ns * 16 + lane15;
      f32x4 v = acc[ms][ns];
      if (BIAS_EN) {
#pragma unroll
        for (int rg = 0; rg < 4; ++rg) v[rg] += bias_l[ns];
      }
      if (RELU_EN) {
#pragma unroll
        for (int rg = 0; rg < 4; ++rg) v[rg] = fmaxf(v[rg], 0.f);
      }
#pragma unroll
      for (int rg = 0; rg < 4; ++rg) {
        const int row = bm + wr + ms * 16 + half * 4 + rg;
        if (row < M) Cp[(size_t)row * CSTRIDE + CBASE + col] = f2bf(v[rg]);
      }
    }
}

// ------------------------------- gathers -----------------------------------
// one wave per node: mean of in-neighbor H2 rows (bf16, Acat cols 256..511)
__global__ __launch_bounds__(256) void gather_mean256_kernel(
    unsigned short* __restrict__ Acat, const int* __restrict__ rowptr,
    const unsigned short* __restrict__ eidx, int M) {
  const int node = blockIdx.x * 4 + (threadIdx.x >> 6);
  if (node >= M) return;
  const int lane = threadIdx.x & 63;
  const int c4 = lane * 4;
  const int beg = rowptr[node], end = rowptr[node + 1];
  float a0 = 0.f, a1 = 0.f, a2 = 0.f, a3 = 0.f;
  int j = beg;
  for (; j + 3 < end; j += 4) {
    const size_t s0 = eidx[j], s1 = eidx[j + 1], s2 = eidx[j + 2], s3 = eidx[j + 3];
    const ushort4 v0 = *(const ushort4*)(Acat + s0 * 512 + 256 + c4);
    const ushort4 v1 = *(const ushort4*)(Acat + s1 * 512 + 256 + c4);
    const ushort4 v2 = *(const ushort4*)(Acat + s2 * 512 + 256 + c4);
    const ushort4 v3 = *(const ushort4*)(Acat + s3 * 512 + 256 + c4);
    a0 += (bf2f(v0.x) + bf2f(v1.x)) + (bf2f(v2.x) + bf2f(v3.x));
    a1 += (bf2f(v0.y) + bf2f(v1.y)) + (bf2f(v2.y) + bf2f(v3.y));
    a2 += (bf2f(v0.z) + bf2f(v1.z)) + (bf2f(v2.z) + bf2f(v3.z));
    a3 += (bf2f(v0.w) + bf2f(v1.w)) + (bf2f(v2.w) + bf2f(v3.w));
  }
  for (; j < end; ++j) {
    const size_t s0 = eidx[j];
    const ushort4 v0 = *(const ushort4*)(Acat + s0 * 512 + 256 + c4);
    a0 += bf2f(v0.x); a1 += bf2f(v0.y); a2 += bf2f(v0.z); a3 += bf2f(v0.w);
  }
  const float inv = 1.0f / fmaxf((float)(end - beg), 1.0f);
  ushort4 o;
  o.x = f2bf(a0 * inv); o.y = f2bf(a1 * inv);
  o.z = f2bf(a2 * inv); o.w = f2bf(a3 * inv);
  *(ushort4*)(Acat + (size_t)node * 512 + c4) = o;
}

// one wave per node: v = mean(T[src]) + bl2 + R ; out = v / max(||v||,1e-12)
// T = Acat cols 256..383, R = Acat cols 384..511
__global__ __launch_bounds__(256) void gather_finalize_kernel(
    const unsigned short* __restrict__ Acat, const int* __restrict__ rowptr,
    const unsigned short* __restrict__ eidx, const float* __restrict__ bl2,
    float* __restrict__ out, int M) {
  const int node = blockIdx.x * 4 + (threadIdx.x >> 6);
  if (node >= M) return;
  const int lane = threadIdx.x & 63;
  const int c2 = lane * 2;
  const int beg = rowptr[node], end = rowptr[node + 1];
  float ax = 0.f, ay = 0.f;
  int j = beg;
  for (; j + 3 < end; j += 4) {
    const size_t s0 = eidx[j], s1 = eidx[j + 1], s2 = eidx[j + 2], s3 = eidx[j + 3];
    const ushort2 v0 = *(const ushort2*)(Acat + s0 * 512 + 256 + c2);
    const ushort2 v1 = *(const ushort2*)(Acat + s1 * 512 + 256 + c2);
    const ushort2 v2 = *(const ushort2*)(Acat + s2 * 512 + 256 + c2);
    const ushort2 v3 = *(const ushort2*)(Acat + s3 * 512 + 256 + c2);
    ax += (bf2f(v0.x) + bf2f(v1.x)) + (bf2f(v2.x) + bf2f(v3.x));
    ay += (bf2f(v0.y) + bf2f(v1.y)) + (bf2f(v2.y) + bf2f(v3.y));
  }
  for (; j < end; ++j) {
    const size_t s0 = eidx[j];
    const ushort2 v0 = *(const ushort2*)(Acat + s0 * 512 + 256 + c2);
    ax += bf2f(v0.x); ay += bf2f(v0.y);
  }
  const float inv = 1.0f / fmaxf((float)(end - beg), 1.0f);
  const ushort2 rr = *(const ushort2*)(Acat + (size_t)node * 512 + 384 + c2);
  const float2 b = *(const float2*)&bl2[c2];
  const float vx = fmaf(ax, inv, b.x) + bf2f(rr.x);
  const float vy = fmaf(ay, inv, b.y) + bf2f(rr.y);
  float ss = vx * vx + vy * vy;
#pragma unroll
  for (int off = 32; off > 0; off >>= 1) ss += __shfl_xor(ss, off);
  const float rn = 1.0f / fmaxf(sqrtf(ss), 1e-12f);
  *(float2*)&out[(size_t)node * 128 + c2] = make_float2(vx * rn, vy * rn);
}

// ---------------------------------------------------------------------------
extern "C" void kernel_launch(void* const* d_in, const int* in_sizes, int n_in,
                              void* d_out, int out_size, void* d_ws, size_t ws_size,
                              hipStream_t stream) {
  const float* x      = (const float*)d_in[0];
  const int*   ei     = (const int*)d_in[1];
  const float* W_pre  = (const float*)d_in[2];
  const float* b_pre  = (const float*)d_in[3];
  const float* W_pre2 = (const float*)d_in[4];
  const float* b_pre2 = (const float*)d_in[5];
  const float* Wl1    = (const float*)d_in[6];
  const float* bl1    = (const float*)d_in[7];
  const float* Wr1    = (const float*)d_in[8];
  const float* Wl2    = (const float*)d_in[9];
  const float* bl2    = (const float*)d_in[10];
  const float* Wr2    = (const float*)d_in[11];
  float* out = (float*)d_out;

  const int M = in_sizes[0] / 512;  // 50000
  const int E = in_sizes[1] / 2;    // 800000
  const int* src = ei;
  const int* dst = ei + E;

  // workspace: Acat bf16[M*512] | H3 bf16[M*256] | xb bf16[M*512] |
  //   Wc[256*512] | Bc1[256*512] | Bc2[256*256] | bc f32[256] | rowptr[M+1] |
  //   cnt[M] | bsum | boff | eidx ushort[E]     (~131 MB)
  char* p = (char*)d_ws;
  unsigned short* Acat = (unsigned short*)p; p += (size_t)M * 512 * 2;
  unsigned short* H3   = (unsigned short*)p; p += (size_t)M * 256 * 2;
  unsigned short* xb   = (unsigned short*)p; p += (size_t)M * 512 * 2;
  unsigned short* Wc   = (unsigned short*)p; p += 256 * 512 * 2;
  unsigned short* Bc1  = (unsigned short*)p; p += 256 * 512 * 2;
  unsigned short* Bc2  = (unsigned short*)p; p += 256 * 256 * 2;
  float* bc   = (float*)p; p += 256 * 4;
  int* rowptr = (int*)p;   p += (size_t)(M + 1) * 4;
  int* cnt    = (int*)p;   p += (size_t)M * 4;
  int* bsum   = (int*)p;   p += 256 * 4;
  int* boff   = (int*)p;   p += 256 * 4;
  unsigned short* eidx = (unsigned short*)p;

  const int eblk = (E + 255) / 256;
  const int nb   = (M + 255) / 256;         // 196
  const int nwg  = ((M + 127) / 128) * 2;   // 782 (1-D grid, XCD-chunked)
  const int nblk = (M + 3) / 4;

  // x -> bf16 (streaming)
  cvt_x_kernel<<<2048, 256, 0, stream>>>(x, xb, M * 512);

  // CSR build
  zero_int_kernel<<<256, 256, 0, stream>>>(cnt, M);
  count_kernel<<<eblk, 256, 0, stream>>>(dst, cnt, E);
  scan_pass1<<<nb, 256, 0, stream>>>(cnt, bsum, M);
  scan_pass2<<<1, 256, 0, stream>>>(bsum, boff, rowptr, nb, M, E);
  scan_pass3<<<nb, 256, 0, stream>>>(cnt, boff, rowptr, M);
  fill_kernel<<<eblk, 256, 0, stream>>>(src, dst, rowptr, cnt, eidx, E);

  // fused weight prep
  prep_kernel<<<1025, 256, 0, stream>>>(W_pre, W_pre2, b_pre, b_pre2,
                                        Wl1, Wr1, Wl2, Wr2, Wc, bc, Bc1, Bc2);

  // H2 = xb @ Wc.T + bc  -> Acat cols 256..511
  mfma_gemm<512, 512, 512, 256, true, false>
      <<<nwg, 256, 0, stream>>>(xb, Wc, bc, Acat, M, nwg);
  // mean1 -> Acat cols 0..255
  gather_mean256_kernel<<<nblk, 256, 0, stream>>>(Acat, rowptr, eidx, M);
  // H3 = relu(Acat @ Bc1.T + bl1)
  mfma_gemm<512, 512, 256, 0, true, true>
      <<<nwg, 256, 0, stream>>>(Acat, Bc1, bl1, H3, M, nwg);
  // TR = H3 @ Bc2.T -> Acat cols 256..511 (H2 dead)
  mfma_gemm<256, 256, 512, 256, false, false>
      <<<nwg, 256, 0, stream>>>(H3, Bc2, nullptr, Acat, M, nwg);
  // out = l2norm(mean(T) + bl2 + R)
  gather_finalize_kernel<<<nblk, 256, 0, stream>>>(Acat, rowptr, eidx, bl2, out, M);
}

// Round 10
// 287.998 us; speedup vs baseline: 1.0930x; 1.0930x over previous
//
#include <hip/hip_runtime.h>
#include <hip/hip_bf16.h>

// ---------------------------------------------------------------------------
// GraphSAGE forward, bf16 MFMA GEMMs (128x128, BK=32, 3-buffer depth-2
// counted-vmcnt pipeline, LDS-transposed coalesced epilogue) + CSR gather.
//   xb  = bf16(x)
//   Wc  = bf16(W_pre2 @ W_pre), bc = W_pre2 @ b_pre + b_pre2
//   Acat[M,512] bf16: cols 0..255 = mean1, cols 256..511 = H2 (later TR)
//   H2  = xb @ Wc.T + bc
//   mean1[n] = mean_{s in N(n)} H2[s]
//   H3  = relu(Acat @ [Wl1|Wr1].T + bl1)
//   TR  = H3 @ [Wl2;Wr2].T  -> overwrites Acat cols 256..511
//   out = l2norm(mean_s(T[s]) + bl2 + R)
// R9 fix vs R8: epilogue image is 128 cols (256B/row); store-back is ONE
// 256B segment per row at CBASE + bn (+bn was missing -> wrote the other
// column block's territory). PITCH=288: half-rows on disjoint bank quartets.
// ---------------------------------------------------------------------------

typedef __attribute__((ext_vector_type(4))) float f32x4;
typedef __attribute__((ext_vector_type(8))) short s8v;

__device__ __forceinline__ float bf2f(unsigned short u) {
  union { unsigned int i; float f; } v; v.i = ((unsigned int)u) << 16; return v.f;
}
__device__ __forceinline__ unsigned short f2bf(float f) {
  unsigned int u = __builtin_bit_cast(unsigned int, f);
  u += 0x7fffu + ((u >> 16) & 1u);          // round-to-nearest-even
  return (unsigned short)(u >> 16);
}

// ------------------------------ CSR build ----------------------------------
__global__ __launch_bounds__(256) void zero_int_kernel(int* __restrict__ p, int n) {
  int i = blockIdx.x * blockDim.x + threadIdx.x;
  const int stride = gridDim.x * blockDim.x;
  for (; i < n; i += stride) p[i] = 0;
}

__global__ __launch_bounds__(256) void count_kernel(const int* __restrict__ dst,
                                                    int* __restrict__ cnt, int E) {
  const int e = blockIdx.x * blockDim.x + threadIdx.x;
  if (e < E) atomicAdd(&cnt[dst[e]], 1);
}

__global__ __launch_bounds__(256) void scan_pass1(const int* __restrict__ cnt,
                                                  int* __restrict__ bsum, int M) {
  __shared__ int red[256];
  const int t = threadIdx.x;
  const int i = blockIdx.x * 256 + t;
  red[t] = (i < M) ? cnt[i] : 0;
  __syncthreads();
  for (int off = 128; off > 0; off >>= 1) {
    if (t < off) red[t] += red[t + off];
    __syncthreads();
  }
  if (t == 0) bsum[blockIdx.x] = red[0];
}

__global__ __launch_bounds__(256) void scan_pass2(const int* __restrict__ bsum,
    int* __restrict__ boff, int* __restrict__ rowptr, int nb, int M, int E) {
  __shared__ int buf[256];
  const int t = threadIdx.x;
  const int v = (t < nb) ? bsum[t] : 0;
  buf[t] = v;
  __syncthreads();
  for (int off = 1; off < 256; off <<= 1) {
    const int add = (t >= off) ? buf[t - off] : 0;
    __syncthreads();
    buf[t] += add;
    __syncthreads();
  }
  if (t < nb) boff[t] = buf[t] - v;
  if (t == 0) rowptr[M] = E;
}

__global__ __launch_bounds__(256) void scan_pass3(int* __restrict__ cnt,
    const int* __restrict__ boff, int* __restrict__ rowptr, int M) {
  __shared__ int buf[256];
  const int t = threadIdx.x;
  const int i = blockIdx.x * 256 + t;
  const int v = (i < M) ? cnt[i] : 0;
  buf[t] = v;
  __syncthreads();
  for (int off = 1; off < 256; off <<= 1) {
    const int add = (t >= off) ? buf[t - off] : 0;
    __syncthreads();
    buf[t] += add;
    __syncthreads();
  }
  if (i < M) {
    rowptr[i] = buf[t] - v + boff[blockIdx.x];
    cnt[i] = 0;   // reset for fill cursor
  }
}

__global__ __launch_bounds__(256) void fill_kernel(const int* __restrict__ src,
    const int* __restrict__ dst, const int* __restrict__ rowptr,
    int* __restrict__ cursor, unsigned short* __restrict__ eidx, int E) {
  const int e = blockIdx.x * blockDim.x + threadIdx.x;
  if (e >= E) return;
  const int d = dst[e];
  const int pos = rowptr[d] + atomicAdd(&cursor[d], 1);
  eidx[pos] = (unsigned short)src[e];
}

// ---------------------- x -> bf16 streaming convert ------------------------
__global__ __launch_bounds__(256) void cvt_x_kernel(const float* __restrict__ x,
    unsigned short* __restrict__ xb, int n) {   // n = M*512, multiple of 8
  int i = (blockIdx.x * 256 + threadIdx.x) * 8;
  const int stride = gridDim.x * 256 * 8;
  for (; i < n; i += stride) {
    const float4 f0 = *(const float4*)(x + i);
    const float4 f1 = *(const float4*)(x + i + 4);
    s8v p;
    p[0] = (short)f2bf(f0.x); p[1] = (short)f2bf(f0.y);
    p[2] = (short)f2bf(f0.z); p[3] = (short)f2bf(f0.w);
    p[4] = (short)f2bf(f1.x); p[5] = (short)f2bf(f1.y);
    p[6] = (short)f2bf(f1.z); p[7] = (short)f2bf(f1.w);
    *(s8v*)(xb + i) = p;
  }
}

// --------------------- fused weight preparation ----------------------------
// blocks 0..255: Wc row o ; block 256: bc ; 257..768: Bc1 ; 769..1024: Bc2
__global__ __launch_bounds__(256) void prep_kernel(const float* __restrict__ Wp,
    const float* __restrict__ Wp2, const float* __restrict__ bp,
    const float* __restrict__ bp2, const float* __restrict__ Wl1,
    const float* __restrict__ Wr1, const float* __restrict__ Wl2,
    const float* __restrict__ Wr2, unsigned short* __restrict__ Wc,
    float* __restrict__ bc, unsigned short* __restrict__ Bc1,
    unsigned short* __restrict__ Bc2) {
  const int b = blockIdx.x, t = threadIdx.x;
  if (b < 256) {
    __shared__ float wrow[256];
    wrow[t] = Wp2[b * 256 + t];
    __syncthreads();
    float a0 = 0.f, a1 = 0.f;
    for (int m = 0; m < 256; ++m) {
      const float w = wrow[m];
      a0 = fmaf(w, Wp[m * 512 + t], a0);
      a1 = fmaf(w, Wp[m * 512 + 256 + t], a1);
    }
    Wc[b * 512 + t] = f2bf(a0);
    Wc[b * 512 + 256 + t] = f2bf(a1);
  } else if (b == 256) {
    float s = 0.f;
    for (int m = 0; m < 256; ++m) s = fmaf(Wp2[t * 256 + m], bp[m], s);
    bc[t] = s + bp2[t];
  } else if (b < 769) {
    const int idx = (b - 257) * 256 + t;   // < 256*512
    const int o = idx >> 9, k = idx & 511;
    const float v = (k < 256) ? Wl1[o * 256 + k] : Wr1[o * 256 + (k - 256)];
    Bc1[idx] = f2bf(v);
  } else {
    const int idx = (b - 769) * 256 + t;   // < 256*256
    const int r = idx >> 8, k = idx & 255;
    const float v = (r < 128) ? Wl2[r * 256 + k] : Wr2[(r - 128) * 256 + k];
    Bc2[idx] = f2bf(v);
  }
}

// ---------------------------------------------------------------------------
// MFMA GEMM: C[M,256] = act(A[M,K] @ B[256,K].T + bias), bf16 in, fp32 acc.
// ---------------------------------------------------------------------------
template <int K, int ASTRIDE, int CSTRIDE, int CBASE, bool BIAS_EN, bool RELU_EN>
__global__ __launch_bounds__(256) void mfma_gemm(
    const unsigned short* __restrict__ Ap, const unsigned short* __restrict__ Bp,
    const float* __restrict__ bias, unsigned short* __restrict__ Cp, int M, int nwg) {
  constexpr int NT = K / 32;
  constexpr int BUF = 16384;           // As 8KB | Bs 8KB per buffer
  __shared__ __align__(16) char smem[3 * BUF];

  // bijective XCD chunking (m204); pair (wg, wg^1) shares A rows on one XCD
  const int xcd = blockIdx.x & 7, bidx = blockIdx.x >> 3;
  const int q = nwg >> 3, r = nwg & 7;
  const int wg = (xcd < r ? xcd * (q + 1) : r * (q + 1) + (xcd - r) * q) + bidx;
  const int bm = (wg >> 1) * 128;
  const int bn = (wg & 1) * 128;

  const int t = threadIdx.x, w = t >> 6, l = t & 63;
  const int wr = (w >> 1) * 64, wc = (w & 1) * 64;
  const int lane15 = l & 15, half = l >> 4;     // half = k-chunk 0..3

  // staging map: thread t covers LDS rows sr (j=0) and 64+sr (j=1),
  // phys slot sp; swizzle slot = sp ^ ((row>>1)&3) (R2-verified: 0 confl.)
  const int sr = t >> 2, sp = t & 3;
  const int ar0 = min(bm + sr, M - 1);
  const int ar1 = min(bm + 64 + sr, M - 1);
  const int sl0 = sp ^ ((sr >> 1) & 3);
  const int sl1 = sp ^ (((64 + sr) >> 1) & 3);
  const unsigned short* apb0 = Ap + (size_t)ar0 * ASTRIDE + sl0 * 8;
  const unsigned short* apb1 = Ap + (size_t)ar1 * ASTRIDE + sl1 * 8;
  const unsigned short* bpb0 = Bp + (size_t)(bn + sr) * K + sl0 * 8;
  const unsigned short* bpb1 = Bp + (size_t)(bn + 64 + sr) * K + sl1 * 8;

  f32x4 acc[4][4];
#pragma unroll
  for (int i = 0; i < 4; ++i)
#pragma unroll
    for (int j = 0; j < 4; ++j) acc[i][j] = f32x4{0.f, 0.f, 0.f, 0.f};

  auto stage = [&](int bufOff, int k0) {   // 4 global_load_lds per thread
    __builtin_amdgcn_global_load_lds((const unsigned int*)(apb0 + k0),
        (unsigned int*)(smem + bufOff + w * 1024), 16, 0, 0);
    __builtin_amdgcn_global_load_lds((const unsigned int*)(apb1 + k0),
        (unsigned int*)(smem + bufOff + 4096 + w * 1024), 16, 0, 0);
    __builtin_amdgcn_global_load_lds((const unsigned int*)(bpb0 + k0),
        (unsigned int*)(smem + bufOff + 8192 + w * 1024), 16, 0, 0);
    __builtin_amdgcn_global_load_lds((const unsigned int*)(bpb1 + k0),
        (unsigned int*)(smem + bufOff + 12288 + w * 1024), 16, 0, 0);
  };
  auto compute = [&](int bufOff) {
    const char* Ab = smem + bufOff;
    const char* Bb = Ab + 8192;
    s8v af[4], bv[4];
#pragma unroll
    for (int ms = 0; ms < 4; ++ms) {
      const int rr = wr + ms * 16 + lane15;
      af[ms] = *(const s8v*)(Ab + rr * 64 + ((half ^ ((rr >> 1) & 3)) << 4));
    }
#pragma unroll
    for (int ns = 0; ns < 4; ++ns) {
      const int rr = wc + ns * 16 + lane15;
      bv[ns] = *(const s8v*)(Bb + rr * 64 + ((half ^ ((rr >> 1) & 3)) << 4));
    }
#pragma unroll
    for (int ms = 0; ms < 4; ++ms)
#pragma unroll
      for (int ns = 0; ns < 4; ++ns)
        acc[ms][ns] =
            __builtin_amdgcn_mfma_f32_16x16x32_bf16(af[ms], bv[ns], acc[ms][ns], 0, 0, 0);
  };

  // --- prologue: two tiles in flight ---
  stage(0, 0);
  stage(BUF, 32);

  int offC = 0, offI = 2 * BUF;
#pragma unroll 1
  for (int tt = 0; tt < NT - 1; ++tt) {
    // S(tt) landed; S(tt+1)'s 4 loads remain in flight across the barrier
    asm volatile("s_waitcnt vmcnt(4)" ::: "memory");
    __builtin_amdgcn_sched_barrier(0);
    __builtin_amdgcn_s_barrier();
    if (tt + 2 < NT) stage(offI, (tt + 2) * 32);
    compute(offC);
    offC = (offC == 2 * BUF) ? 0 : offC + BUF;
    offI = (offI == 2 * BUF) ? 0 : offI + BUF;
  }
  asm volatile("s_waitcnt vmcnt(0)" ::: "memory");
  __builtin_amdgcn_sched_barrier(0);
  __builtin_amdgcn_s_barrier();
  compute(offC);

  // --- epilogue: coalesced C store via LDS transpose (2 passes x 64 rows,
  //     128 cols = 256B per row) ---
  float bias_l[4];
  if (BIAS_EN) {
#pragma unroll
    for (int ns = 0; ns < 4; ++ns) bias_l[ns] = bias[bn + wc + ns * 16 + lane15];
  }
  constexpr int PITCH = 288;   // 256B row + 32B pad: 4 half-rows of one
                               // ds_write_b16 hit disjoint bank quartets
#pragma unroll
  for (int pp = 0; pp < 2; ++pp) {
    __syncthreads();           // LDS free (compute / prev-pass reads done)
#pragma unroll
    for (int mi = 0; mi < 2; ++mi) {
      const int ms = 2 * pp + mi;
      const int lrow0 = (wr >> 1) + (mi << 4) + half * 4;   // 0..63
#pragma unroll
      for (int ns = 0; ns < 4; ++ns) {
        f32x4 v = acc[ms][ns];
        if (BIAS_EN) {
#pragma unroll
          for (int rg = 0; rg < 4; ++rg) v[rg] += bias_l[ns];
        }
        if (RELU_EN) {
#pragma unroll
          for (int rg = 0; rg < 4; ++rg) v[rg] = fmaxf(v[rg], 0.f);
        }
        const int colb = (wc + ns * 16 + lane15) * 2;   // local col byte
#pragma unroll
        for (int rg = 0; rg < 4; ++rg)
          *(unsigned short*)(smem + (lrow0 + rg) * PITCH + colb) = f2bf(v[rg]);
      }
    }
    __syncthreads();           // LDS image complete
    // 64 rows x 256B: one 16-lane group per row, 16B per lane, contiguous
#pragma unroll
    for (int jj = 0; jj < 4; ++jj) {
      const int lr = jj * 16 + (t >> 4);            // 0..63
      const int wrg = (lr >= 32) ? 64 : 0;
      const int msg = 2 * pp + ((lr >> 4) & 1);
      const int grow = bm + wrg + msg * 16 + (lr & 15);
      if (grow < M) {
        const s8v val = *(const s8v*)(smem + lr * PITCH + lane15 * 16);
        *(s8v*)(Cp + (size_t)grow * CSTRIDE + CBASE + bn + lane15 * 8) = val;
      }
    }
  }
}

// ------------------------------- gathers -----------------------------------
// one wave per node: mean of in-neighbor H2 rows (bf16, Acat cols 256..511)
__global__ __launch_bounds__(256) void gather_mean256_kernel(
    unsigned short* __restrict__ Acat, const int* __restrict__ rowptr,
    const unsigned short* __restrict__ eidx, int M) {
  const int node = blockIdx.x * 4 + (threadIdx.x >> 6);
  if (node >= M) return;
  const int lane = threadIdx.x & 63;
  const int c4 = lane * 4;
  const int beg = rowptr[node], end = rowptr[node + 1];
  float a0 = 0.f, a1 = 0.f, a2 = 0.f, a3 = 0.f;
  int j = beg;
  for (; j + 3 < end; j += 4) {
    const size_t s0 = eidx[j], s1 = eidx[j + 1], s2 = eidx[j + 2], s3 = eidx[j + 3];
    const ushort4 v0 = *(const ushort4*)(Acat + s0 * 512 + 256 + c4);
    const ushort4 v1 = *(const ushort4*)(Acat + s1 * 512 + 256 + c4);
    const ushort4 v2 = *(const ushort4*)(Acat + s2 * 512 + 256 + c4);
    const ushort4 v3 = *(const ushort4*)(Acat + s3 * 512 + 256 + c4);
    a0 += (bf2f(v0.x) + bf2f(v1.x)) + (bf2f(v2.x) + bf2f(v3.x));
    a1 += (bf2f(v0.y) + bf2f(v1.y)) + (bf2f(v2.y) + bf2f(v3.y));
    a2 += (bf2f(v0.z) + bf2f(v1.z)) + (bf2f(v2.z) + bf2f(v3.z));
    a3 += (bf2f(v0.w) + bf2f(v1.w)) + (bf2f(v2.w) + bf2f(v3.w));
  }
  for (; j < end; ++j) {
    const size_t s0 = eidx[j];
    const ushort4 v0 = *(const ushort4*)(Acat + s0 * 512 + 256 + c4);
    a0 += bf2f(v0.x); a1 += bf2f(v0.y); a2 += bf2f(v0.z); a3 += bf2f(v0.w);
  }
  const float inv = 1.0f / fmaxf((float)(end - beg), 1.0f);
  ushort4 o;
  o.x = f2bf(a0 * inv); o.y = f2bf(a1 * inv);
  o.z = f2bf(a2 * inv); o.w = f2bf(a3 * inv);
  *(ushort4*)(Acat + (size_t)node * 512 + c4) = o;
}

// one wave per node: v = mean(T[src]) + bl2 + R ; out = v / max(||v||,1e-12)
// T = Acat cols 256..383, R = Acat cols 384..511
__global__ __launch_bounds__(256) void gather_finalize_kernel(
    const unsigned short* __restrict__ Acat, const int* __restrict__ rowptr,
    const unsigned short* __restrict__ eidx, const float* __restrict__ bl2,
    float* __restrict__ out, int M) {
  const int node = blockIdx.x * 4 + (threadIdx.x >> 6);
  if (node >= M) return;
  const int lane = threadIdx.x & 63;
  const int c2 = lane * 2;
  const int beg = rowptr[node], end = rowptr[node + 1];
  float ax = 0.f, ay = 0.f;
  int j = beg;
  for (; j + 3 < end; j += 4) {
    const size_t s0 = eidx[j], s1 = eidx[j + 1], s2 = eidx[j + 2], s3 = eidx[j + 3];
    const ushort2 v0 = *(const ushort2*)(Acat + s0 * 512 + 256 + c2);
    const ushort2 v1 = *(const ushort2*)(Acat + s1 * 512 + 256 + c2);
    const ushort2 v2 = *(const ushort2*)(Acat + s2 * 512 + 256 + c2);
    const ushort2 v3 = *(const ushort2*)(Acat + s3 * 512 + 256 + c2);
    ax += (bf2f(v0.x) + bf2f(v1.x)) + (bf2f(v2.x) + bf2f(v3.x));
    ay += (bf2f(v0.y) + bf2f(v1.y)) + (bf2f(v2.y) + bf2f(v3.y));
  }
  for (; j < end; ++j) {
    const size_t s0 = eidx[j];
    const ushort2 v0 = *(const ushort2*)(Acat + s0 * 512 + 256 + c2);
    ax += bf2f(v0.x); ay += bf2f(v0.y);
  }
  const float inv = 1.0f / fmaxf((float)(end - beg), 1.0f);
  const ushort2 rr = *(const ushort2*)(Acat + (size_t)node * 512 + 384 + c2);
  const float2 b = *(const float2*)&bl2[c2];
  const float vx = fmaf(ax, inv, b.x) + bf2f(rr.x);
  const float vy = fmaf(ay, inv, b.y) + bf2f(rr.y);
  float ss = vx * vx + vy * vy;
#pragma unroll
  for (int off = 32; off > 0; off >>= 1) ss += __shfl_xor(ss, off);
  const float rn = 1.0f / fmaxf(sqrtf(ss), 1e-12f);
  *(float2*)&out[(size_t)node * 128 + c2] = make_float2(vx * rn, vy * rn);
}

// ---------------------------------------------------------------------------
extern "C" void kernel_launch(void* const* d_in, const int* in_sizes, int n_in,
                              void* d_out, int out_size, void* d_ws, size_t ws_size,
                              hipStream_t stream) {
  const float* x      = (const float*)d_in[0];
  const int*   ei     = (const int*)d_in[1];
  const float* W_pre  = (const float*)d_in[2];
  const float* b_pre  = (const float*)d_in[3];
  const float* W_pre2 = (const float*)d_in[4];
  const float* b_pre2 = (const float*)d_in[5];
  const float* Wl1    = (const float*)d_in[6];
  const float* bl1    = (const float*)d_in[7];
  const float* Wr1    = (const float*)d_in[8];
  const float* Wl2    = (const float*)d_in[9];
  const float* bl2    = (const float*)d_in[10];
  const float* Wr2    = (const float*)d_in[11];
  float* out = (float*)d_out;

  const int M = in_sizes[0] / 512;  // 50000
  const int E = in_sizes[1] / 2;    // 800000
  const int* src = ei;
  const int* dst = ei + E;

  // workspace: Acat bf16[M*512] | H3 bf16[M*256] | xb bf16[M*512] |
  //   Wc[256*512] | Bc1[256*512] | Bc2[256*256] | bc f32[256] | rowptr[M+1] |
  //   cnt[M] | bsum | boff | eidx ushort[E]     (~131 MB)
  char* p = (char*)d_ws;
  unsigned short* Acat = (unsigned short*)p; p += (size_t)M * 512 * 2;
  unsigned short* H3   = (unsigned short*)p; p += (size_t)M * 256 * 2;
  unsigned short* xb   = (unsigned short*)p; p += (size_t)M * 512 * 2;
  unsigned short* Wc   = (unsigned short*)p; p += 256 * 512 * 2;
  unsigned short* Bc1  = (unsigned short*)p; p += 256 * 512 * 2;
  unsigned short* Bc2  = (unsigned short*)p; p += 256 * 256 * 2;
  float* bc   = (float*)p; p += 256 * 4;
  int* rowptr = (int*)p;   p += (size_t)(M + 1) * 4;
  int* cnt    = (int*)p;   p += (size_t)M * 4;
  int* bsum   = (int*)p;   p += 256 * 4;
  int* boff   = (int*)p;   p += 256 * 4;
  unsigned short* eidx = (unsigned short*)p;

  const int eblk = (E + 255) / 256;
  const int nb   = (M + 255) / 256;         // 196
  const int nwg  = ((M + 127) / 128) * 2;   // 782 (1-D grid, XCD-chunked)
  const int nblk = (M + 3) / 4;

  // x -> bf16 (streaming)
  cvt_x_kernel<<<2048, 256, 0, stream>>>(x, xb, M * 512);

  // CSR build
  zero_int_kernel<<<256, 256, 0, stream>>>(cnt, M);
  count_kernel<<<eblk, 256, 0, stream>>>(dst, cnt, E);
  scan_pass1<<<nb, 256, 0, stream>>>(cnt, bsum, M);
  scan_pass2<<<1, 256, 0, stream>>>(bsum, boff, rowptr, nb, M, E);
  scan_pass3<<<nb, 256, 0, stream>>>(cnt, boff, rowptr, M);
  fill_kernel<<<eblk, 256, 0, stream>>>(src, dst, rowptr, cnt, eidx, E);

  // fused weight prep
  prep_kernel<<<1025, 256, 0, stream>>>(W_pre, W_pre2, b_pre, b_pre2,
                                        Wl1, Wr1, Wl2, Wr2, Wc, bc, Bc1, Bc2);

  // H2 = xb @ Wc.T + bc  -> Acat cols 256..511
  mfma_gemm<512, 512, 512, 256, true, false>
      <<<nwg, 256, 0, stream>>>(xb, Wc, bc, Acat, M, nwg);
  // mean1 -> Acat cols 0..255
  gather_mean256_kernel<<<nblk, 256, 0, stream>>>(Acat, rowptr, eidx, M);
  // H3 = relu(Acat @ Bc1.T + bl1)
  mfma_gemm<512, 512, 256, 0, true, true>
      <<<nwg, 256, 0, stream>>>(Acat, Bc1, bl1, H3, M, nwg);
  // TR = H3 @ Bc2.T -> Acat cols 256..511 (H2 dead)
  mfma_gemm<256, 256, 512, 256, false, false>
      <<<nwg, 256, 0, stream>>>(H3, Bc2, nullptr, Acat, M, nwg);
  // out = l2norm(mean(T) + bl2 + R)
  gather_finalize_kernel<<<nblk, 256, 0, stream>>>(Acat, rowptr, eidx, bl2, out, M);
}

// Round 11
// 276.678 us; speedup vs baseline: 1.1377x; 1.0409x over previous
//
#include <hip/hip_runtime.h>
#include <hip/hip_bf16.h>

// ---------------------------------------------------------------------------
// GraphSAGE forward, bf16 MFMA GEMMs (128x128, BK=32, 3-buffer depth-2
// counted-vmcnt pipeline, LDS-transposed coalesced epilogue) + CSR gather.
//   Wc  = bf16(W_pre2 @ W_pre), bc = W_pre2 @ b_pre + b_pre2
//   Acat[M,512] bf16: cols 0..255 = mean1, cols 256..511 = H2 (later TR)
//   H2  = x @ Wc.T + bc        (fp32 A fused: reg-load early, cvt+ds_write
//                               one iteration later — T14 split in-pipeline)
//   mean1[n] = mean_{s in N(n)} H2[s]
//   H3  = relu(Acat @ [Wl1|Wr1].T + bl1)
//   TR  = H3 @ [Wl2;Wr2].T  -> overwrites Acat cols 256..511
//   out = l2norm(mean_s(T[s]) + bl2 + R)
// R10 change: cvt_x pass (~33us of pure BW) removed; GEMM1 consumes fp32 x
// directly. Pipeline per iter (A_FP32): vmcnt(2) [A(t+1) regs + B(t) landed,
// B(t+1) stays in flight] -> ds_write A(t+1) -> lgkmcnt(0) -> s_barrier ->
// issue A-regs(t+2) + B-stage(t+2) -> compute(t).
// ---------------------------------------------------------------------------

typedef __attribute__((ext_vector_type(4))) float f32x4;
typedef __attribute__((ext_vector_type(8))) short s8v;

__device__ __forceinline__ float bf2f(unsigned short u) {
  union { unsigned int i; float f; } v; v.i = ((unsigned int)u) << 16; return v.f;
}
__device__ __forceinline__ unsigned short f2bf(float f) {
  unsigned int u = __builtin_bit_cast(unsigned int, f);
  u += 0x7fffu + ((u >> 16) & 1u);          // round-to-nearest-even
  return (unsigned short)(u >> 16);
}

// ------------------------------ CSR build ----------------------------------
__global__ __launch_bounds__(256) void zero_int_kernel(int* __restrict__ p, int n) {
  int i = blockIdx.x * blockDim.x + threadIdx.x;
  const int stride = gridDim.x * blockDim.x;
  for (; i < n; i += stride) p[i] = 0;
}

__global__ __launch_bounds__(256) void count_kernel(const int* __restrict__ dst,
                                                    int* __restrict__ cnt, int E) {
  const int e = blockIdx.x * blockDim.x + threadIdx.x;
  if (e < E) atomicAdd(&cnt[dst[e]], 1);
}

__global__ __launch_bounds__(256) void scan_pass1(const int* __restrict__ cnt,
                                                  int* __restrict__ bsum, int M) {
  __shared__ int red[256];
  const int t = threadIdx.x;
  const int i = blockIdx.x * 256 + t;
  red[t] = (i < M) ? cnt[i] : 0;
  __syncthreads();
  for (int off = 128; off > 0; off >>= 1) {
    if (t < off) red[t] += red[t + off];
    __syncthreads();
  }
  if (t == 0) bsum[blockIdx.x] = red[0];
}

__global__ __launch_bounds__(256) void scan_pass2(const int* __restrict__ bsum,
    int* __restrict__ boff, int* __restrict__ rowptr, int nb, int M, int E) {
  __shared__ int buf[256];
  const int t = threadIdx.x;
  const int v = (t < nb) ? bsum[t] : 0;
  buf[t] = v;
  __syncthreads();
  for (int off = 1; off < 256; off <<= 1) {
    const int add = (t >= off) ? buf[t - off] : 0;
    __syncthreads();
    buf[t] += add;
    __syncthreads();
  }
  if (t < nb) boff[t] = buf[t] - v;
  if (t == 0) rowptr[M] = E;
}

__global__ __launch_bounds__(256) void scan_pass3(int* __restrict__ cnt,
    const int* __restrict__ boff, int* __restrict__ rowptr, int M) {
  __shared__ int buf[256];
  const int t = threadIdx.x;
  const int i = blockIdx.x * 256 + t;
  const int v = (i < M) ? cnt[i] : 0;
  buf[t] = v;
  __syncthreads();
  for (int off = 1; off < 256; off <<= 1) {
    const int add = (t >= off) ? buf[t - off] : 0;
    __syncthreads();
    buf[t] += add;
    __syncthreads();
  }
  if (i < M) {
    rowptr[i] = buf[t] - v + boff[blockIdx.x];
    cnt[i] = 0;   // reset for fill cursor
  }
}

__global__ __launch_bounds__(256) void fill_kernel(const int* __restrict__ src,
    const int* __restrict__ dst, const int* __restrict__ rowptr,
    int* __restrict__ cursor, unsigned short* __restrict__ eidx, int E) {
  const int e = blockIdx.x * blockDim.x + threadIdx.x;
  if (e >= E) return;
  const int d = dst[e];
  const int pos = rowptr[d] + atomicAdd(&cursor[d], 1);
  eidx[pos] = (unsigned short)src[e];
}

// --------------------- fused weight preparation ----------------------------
// blocks 0..255: Wc row o ; block 256: bc ; 257..768: Bc1 ; 769..1024: Bc2
__global__ __launch_bounds__(256) void prep_kernel(const float* __restrict__ Wp,
    const float* __restrict__ Wp2, const float* __restrict__ bp,
    const float* __restrict__ bp2, const float* __restrict__ Wl1,
    const float* __restrict__ Wr1, const float* __restrict__ Wl2,
    const float* __restrict__ Wr2, unsigned short* __restrict__ Wc,
    float* __restrict__ bc, unsigned short* __restrict__ Bc1,
    unsigned short* __restrict__ Bc2) {
  const int b = blockIdx.x, t = threadIdx.x;
  if (b < 256) {
    __shared__ float wrow[256];
    wrow[t] = Wp2[b * 256 + t];
    __syncthreads();
    float a0 = 0.f, a1 = 0.f;
    for (int m = 0; m < 256; ++m) {
      const float w = wrow[m];
      a0 = fmaf(w, Wp[m * 512 + t], a0);
      a1 = fmaf(w, Wp[m * 512 + 256 + t], a1);
    }
    Wc[b * 512 + t] = f2bf(a0);
    Wc[b * 512 + 256 + t] = f2bf(a1);
  } else if (b == 256) {
    float s = 0.f;
    for (int m = 0; m < 256; ++m) s = fmaf(Wp2[t * 256 + m], bp[m], s);
    bc[t] = s + bp2[t];
  } else if (b < 769) {
    const int idx = (b - 257) * 256 + t;   // < 256*512
    const int o = idx >> 9, k = idx & 511;
    const float v = (k < 256) ? Wl1[o * 256 + k] : Wr1[o * 256 + (k - 256)];
    Bc1[idx] = f2bf(v);
  } else {
    const int idx = (b - 769) * 256 + t;   // < 256*256
    const int r = idx >> 8, k = idx & 255;
    const float v = (r < 128) ? Wl2[r * 256 + k] : Wr2[(r - 128) * 256 + k];
    Bc2[idx] = f2bf(v);
  }
}

// ---------------------------------------------------------------------------
// MFMA GEMM: C[M,256] = act(A[M,K] @ B[256,K].T + bias), fp32 acc, bf16 out.
// A is bf16 (global_load_lds staged) or fp32 (reg-staged, cvt, ds_write).
// ---------------------------------------------------------------------------
template <int K, int ASTRIDE, int CSTRIDE, int CBASE, bool BIAS_EN, bool RELU_EN, bool A_FP32>
__global__ __launch_bounds__(256) void mfma_gemm(const void* __restrict__ Ap,
    const unsigned short* __restrict__ Bp, const float* __restrict__ bias,
    unsigned short* __restrict__ Cp, int M, int nwg) {
  constexpr int NT = K / 32;
  constexpr int BUF = 16384;           // As 8KB (bf16) | Bs 8KB per buffer
  __shared__ __align__(16) char smem[3 * BUF];

  // bijective XCD chunking (m204); pair (wg, wg^1) shares A rows on one XCD
  const int xcd = blockIdx.x & 7, bidx = blockIdx.x >> 3;
  const int q = nwg >> 3, r = nwg & 7;
  const int wg = (xcd < r ? xcd * (q + 1) : r * (q + 1) + (xcd - r) * q) + bidx;
  const int bm = (wg >> 1) * 128;
  const int bn = (wg & 1) * 128;

  const int t = threadIdx.x, w = t >> 6, l = t & 63;
  const int wr = (w >> 1) * 64, wc = (w & 1) * 64;
  const int lane15 = l & 15, half = l >> 4;     // half = k-chunk 0..3

  // bf16 staging map (swizzle slot = sp ^ ((row>>1)&3), R2-verified 0-confl.)
  const int sr = t >> 2, sp = t & 3;
  const int sl0 = sp ^ ((sr >> 1) & 3);
  const int sl1 = sp ^ (((64 + sr) >> 1) & 3);
  const unsigned short* Abf = (const unsigned short*)Ap;
  const unsigned short* apb0 = Abf + (size_t)min(bm + sr, M - 1) * ASTRIDE + sl0 * 8;
  const unsigned short* apb1 = Abf + (size_t)min(bm + 64 + sr, M - 1) * ASTRIDE + sl1 * 8;
  const unsigned short* bpb0 = Bp + (size_t)(bn + sr) * K + sl0 * 8;
  const unsigned short* bpb1 = Bp + (size_t)(bn + 64 + sr) * K + sl1 * 8;

  // fp32-A map: thread t -> row fr, half-row fh (16 floats), 2 bf16x8 slots
  const int fr = t >> 1, fh = t & 1;
  const float* Afp = (const float*)Ap + (size_t)min(bm + fr, M - 1) * ASTRIDE + fh * 16;
  const int fs0 = (2 * fh + 0) ^ ((fr >> 1) & 3);
  const int fs1 = (2 * fh + 1) ^ ((fr >> 1) & 3);

  f32x4 acc[4][4];
#pragma unroll
  for (int i = 0; i < 4; ++i)
#pragma unroll
    for (int j = 0; j < 4; ++j) acc[i][j] = f32x4{0.f, 0.f, 0.f, 0.f};

  auto stageAll = [&](int bufOff, int k0) {   // bf16 path: 4 load_lds
    __builtin_amdgcn_global_load_lds((const unsigned int*)(apb0 + k0),
        (unsigned int*)(smem + bufOff + w * 1024), 16, 0, 0);
    __builtin_amdgcn_global_load_lds((const unsigned int*)(apb1 + k0),
        (unsigned int*)(smem + bufOff + 4096 + w * 1024), 16, 0, 0);
    __builtin_amdgcn_global_load_lds((const unsigned int*)(bpb0 + k0),
        (unsigned int*)(smem + bufOff + 8192 + w * 1024), 16, 0, 0);
    __builtin_amdgcn_global_load_lds((const unsigned int*)(bpb1 + k0),
        (unsigned int*)(smem + bufOff + 12288 + w * 1024), 16, 0, 0);
  };
  auto stageB2 = [&](int bufOff, int k0) {    // fp32 path: B only
    __builtin_amdgcn_global_load_lds((const unsigned int*)(bpb0 + k0),
        (unsigned int*)(smem + bufOff + 8192 + w * 1024), 16, 0, 0);
    __builtin_amdgcn_global_load_lds((const unsigned int*)(bpb1 + k0),
        (unsigned int*)(smem + bufOff + 12288 + w * 1024), 16, 0, 0);
  };
  auto loadA = [&](int k0, float4* ar) {
    ar[0] = *(const float4*)(Afp + k0 + 0);
    ar[1] = *(const float4*)(Afp + k0 + 4);
    ar[2] = *(const float4*)(Afp + k0 + 8);
    ar[3] = *(const float4*)(Afp + k0 + 12);
  };
  auto writeA = [&](int bufOff, const float4* ar) {
    s8v p0, p1;
    p0[0] = (short)f2bf(ar[0].x); p0[1] = (short)f2bf(ar[0].y);
    p0[2] = (short)f2bf(ar[0].z); p0[3] = (short)f2bf(ar[0].w);
    p0[4] = (short)f2bf(ar[1].x); p0[5] = (short)f2bf(ar[1].y);
    p0[6] = (short)f2bf(ar[1].z); p0[7] = (short)f2bf(ar[1].w);
    p1[0] = (short)f2bf(ar[2].x); p1[1] = (short)f2bf(ar[2].y);
    p1[2] = (short)f2bf(ar[2].z); p1[3] = (short)f2bf(ar[2].w);
    p1[4] = (short)f2bf(ar[3].x); p1[5] = (short)f2bf(ar[3].y);
    p1[6] = (short)f2bf(ar[3].z); p1[7] = (short)f2bf(ar[3].w);
    *(s8v*)(smem + bufOff + fr * 64 + fs0 * 16) = p0;
    *(s8v*)(smem + bufOff + fr * 64 + fs1 * 16) = p1;
  };
  auto compute = [&](int bufOff) {
    const char* Ab = smem + bufOff;
    const char* Bb = Ab + 8192;
    s8v af[4], bv[4];
#pragma unroll
    for (int ms = 0; ms < 4; ++ms) {
      const int rr = wr + ms * 16 + lane15;
      af[ms] = *(const s8v*)(Ab + rr * 64 + ((half ^ ((rr >> 1) & 3)) << 4));
    }
#pragma unroll
    for (int ns = 0; ns < 4; ++ns) {
      const int rr = wc + ns * 16 + lane15;
      bv[ns] = *(const s8v*)(Bb + rr * 64 + ((half ^ ((rr >> 1) & 3)) << 4));
    }
#pragma unroll
    for (int ms = 0; ms < 4; ++ms)
#pragma unroll
      for (int ns = 0; ns < 4; ++ns)
        acc[ms][ns] =
            __builtin_amdgcn_mfma_f32_16x16x32_bf16(af[ms], bv[ns], acc[ms][ns], 0, 0, 0);
  };

  if constexpr (A_FP32) {
    static_assert(NT % 2 == 0, "fp32 path assumes even NT");
    float4 arE[4], arO[4];
    // prologue: A(0),B(0),A(1),B(1) in flight; A(0) written once landed
    loadA(0, arE);
    __builtin_amdgcn_sched_barrier(0);
    stageB2(0, 0);
    __builtin_amdgcn_sched_barrier(0);
    loadA(32, arO);
    __builtin_amdgcn_sched_barrier(0);
    stageB2(BUF, 32);
    __builtin_amdgcn_sched_barrier(0);
    writeA(0, arE);              // compiler inserts the A(0) vmcnt wait

    auto iterF = [&](int tt, int ofC, int ofW, int ofI,
                     float4 (&arW)[4], float4 (&arI)[4]) {
      asm volatile("s_waitcnt vmcnt(2)" ::: "memory");  // A(tt+1)+B(tt) landed
      __builtin_amdgcn_sched_barrier(0);
      writeA(ofW, arW);                                 // A(tt+1) -> LDS
      asm volatile("s_waitcnt lgkmcnt(0)" ::: "memory");
      __builtin_amdgcn_sched_barrier(0);
      __builtin_amdgcn_s_barrier();
      if (tt + 2 < NT) {
        loadA((tt + 2) * 32, arI);
        __builtin_amdgcn_sched_barrier(0);
        stageB2(ofI, (tt + 2) * 32);
        __builtin_amdgcn_sched_barrier(0);
      }
      compute(ofC);
    };
    auto rot = [](int o) { return o == 2 * BUF ? 0 : o + BUF; };
    int ofC = 0, ofW = BUF, ofI = 2 * BUF;
#pragma unroll 1
    for (int tt = 0; tt + 1 < NT - 1; tt += 2) {
      iterF(tt, ofC, ofW, ofI, arO, arE);
      ofC = rot(ofC); ofW = rot(ofW); ofI = rot(ofI);
      iterF(tt + 1, ofC, ofW, ofI, arE, arO);
      ofC = rot(ofC); ofW = rot(ofW); ofI = rot(ofI);
    }
    iterF(NT - 2, ofC, ofW, ofI, arO, arE);   // writes A(NT-1), no new issue beyond
    ofC = rot(ofC);
    asm volatile("s_waitcnt vmcnt(0)" ::: "memory");
    __builtin_amdgcn_sched_barrier(0);
    __builtin_amdgcn_s_barrier();
    compute(ofC);
  } else {
    // prologue: two tiles in flight
    stageAll(0, 0);
    stageAll(BUF, 32);
    int offC = 0, offI = 2 * BUF;
#pragma unroll 1
    for (int tt = 0; tt < NT - 1; ++tt) {
      asm volatile("s_waitcnt vmcnt(4)" ::: "memory");  // S(tt) landed
      __builtin_amdgcn_sched_barrier(0);
      __builtin_amdgcn_s_barrier();
      if (tt + 2 < NT) stageAll(offI, (tt + 2) * 32);
      compute(offC);
      offC = (offC == 2 * BUF) ? 0 : offC + BUF;
      offI = (offI == 2 * BUF) ? 0 : offI + BUF;
    }
    asm volatile("s_waitcnt vmcnt(0)" ::: "memory");
    __builtin_amdgcn_sched_barrier(0);
    __builtin_amdgcn_s_barrier();
    compute(offC);
  }

  // --- epilogue: coalesced C store via LDS transpose (2 passes x 64 rows,
  //     128 cols = 256B per row) ---
  float bias_l[4];
  if (BIAS_EN) {
#pragma unroll
    for (int ns = 0; ns < 4; ++ns) bias_l[ns] = bias[bn + wc + ns * 16 + lane15];
  }
  constexpr int PITCH = 288;   // 256B row + 32B pad
#pragma unroll
  for (int pp = 0; pp < 2; ++pp) {
    __syncthreads();           // LDS free (compute / prev-pass reads done)
#pragma unroll
    for (int mi = 0; mi < 2; ++mi) {
      const int ms = 2 * pp + mi;
      const int lrow0 = (wr >> 1) + (mi << 4) + half * 4;   // 0..63
#pragma unroll
      for (int ns = 0; ns < 4; ++ns) {
        f32x4 v = acc[ms][ns];
        if (BIAS_EN) {
#pragma unroll
          for (int rg = 0; rg < 4; ++rg) v[rg] += bias_l[ns];
        }
        if (RELU_EN) {
#pragma unroll
          for (int rg = 0; rg < 4; ++rg) v[rg] = fmaxf(v[rg], 0.f);
        }
        const int colb = (wc + ns * 16 + lane15) * 2;   // local col byte
#pragma unroll
        for (int rg = 0; rg < 4; ++rg)
          *(unsigned short*)(smem + (lrow0 + rg) * PITCH + colb) = f2bf(v[rg]);
      }
    }
    __syncthreads();           // LDS image complete
    // 64 rows x 256B: one 16-lane group per row, 16B per lane, contiguous
#pragma unroll
    for (int jj = 0; jj < 4; ++jj) {
      const int lr = jj * 16 + (t >> 4);            // 0..63
      const int wrg = (lr >= 32) ? 64 : 0;
      const int msg = 2 * pp + ((lr >> 4) & 1);
      const int grow = bm + wrg + msg * 16 + (lr & 15);
      if (grow < M) {
        const s8v val = *(const s8v*)(smem + lr * PITCH + lane15 * 16);
        *(s8v*)(Cp + (size_t)grow * CSTRIDE + CBASE + bn + lane15 * 8) = val;
      }
    }
  }
}

// ------------------------------- gathers -----------------------------------
// one wave per node: mean of in-neighbor H2 rows (bf16, Acat cols 256..511)
__global__ __launch_bounds__(256) void gather_mean256_kernel(
    unsigned short* __restrict__ Acat, const int* __restrict__ rowptr,
    const unsigned short* __restrict__ eidx, int M) {
  const int node = blockIdx.x * 4 + (threadIdx.x >> 6);
  if (node >= M) return;
  const int lane = threadIdx.x & 63;
  const int c4 = lane * 4;
  const int beg = rowptr[node], end = rowptr[node + 1];
  float a0 = 0.f, a1 = 0.f, a2 = 0.f, a3 = 0.f;
  int j = beg;
  for (; j + 3 < end; j += 4) {
    const size_t s0 = eidx[j], s1 = eidx[j + 1], s2 = eidx[j + 2], s3 = eidx[j + 3];
    const ushort4 v0 = *(const ushort4*)(Acat + s0 * 512 + 256 + c4);
    const ushort4 v1 = *(const ushort4*)(Acat + s1 * 512 + 256 + c4);
    const ushort4 v2 = *(const ushort4*)(Acat + s2 * 512 + 256 + c4);
    const ushort4 v3 = *(const ushort4*)(Acat + s3 * 512 + 256 + c4);
    a0 += (bf2f(v0.x) + bf2f(v1.x)) + (bf2f(v2.x) + bf2f(v3.x));
    a1 += (bf2f(v0.y) + bf2f(v1.y)) + (bf2f(v2.y) + bf2f(v3.y));
    a2 += (bf2f(v0.z) + bf2f(v1.z)) + (bf2f(v2.z) + bf2f(v3.z));
    a3 += (bf2f(v0.w) + bf2f(v1.w)) + (bf2f(v2.w) + bf2f(v3.w));
  }
  for (; j < end; ++j) {
    const size_t s0 = eidx[j];
    const ushort4 v0 = *(const ushort4*)(Acat + s0 * 512 + 256 + c4);
    a0 += bf2f(v0.x); a1 += bf2f(v0.y); a2 += bf2f(v0.z); a3 += bf2f(v0.w);
  }
  const float inv = 1.0f / fmaxf((float)(end - beg), 1.0f);
  ushort4 o;
  o.x = f2bf(a0 * inv); o.y = f2bf(a1 * inv);
  o.z = f2bf(a2 * inv); o.w = f2bf(a3 * inv);
  *(ushort4*)(Acat + (size_t)node * 512 + c4) = o;
}

// one wave per node: v = mean(T[src]) + bl2 + R ; out = v / max(||v||,1e-12)
// T = Acat cols 256..383, R = Acat cols 384..511
__global__ __launch_bounds__(256) void gather_finalize_kernel(
    const unsigned short* __restrict__ Acat, const int* __restrict__ rowptr,
    const unsigned short* __restrict__ eidx, const float* __restrict__ bl2,
    float* __restrict__ out, int M) {
  const int node = blockIdx.x * 4 + (threadIdx.x >> 6);
  if (node >= M) return;
  const int lane = threadIdx.x & 63;
  const int c2 = lane * 2;
  const int beg = rowptr[node], end = rowptr[node + 1];
  float ax = 0.f, ay = 0.f;
  int j = beg;
  for (; j + 3 < end; j += 4) {
    const size_t s0 = eidx[j], s1 = eidx[j + 1], s2 = eidx[j + 2], s3 = eidx[j + 3];
    const ushort2 v0 = *(const ushort2*)(Acat + s0 * 512 + 256 + c2);
    const ushort2 v1 = *(const ushort2*)(Acat + s1 * 512 + 256 + c2);
    const ushort2 v2 = *(const ushort2*)(Acat + s2 * 512 + 256 + c2);
    const ushort2 v3 = *(const ushort2*)(Acat + s3 * 512 + 256 + c2);
    ax += (bf2f(v0.x) + bf2f(v1.x)) + (bf2f(v2.x) + bf2f(v3.x));
    ay += (bf2f(v0.y) + bf2f(v1.y)) + (bf2f(v2.y) + bf2f(v3.y));
  }
  for (; j < end; ++j) {
    const size_t s0 = eidx[j];
    const ushort2 v0 = *(const ushort2*)(Acat + s0 * 512 + 256 + c2);
    ax += bf2f(v0.x); ay += bf2f(v0.y);
  }
  const float inv = 1.0f / fmaxf((float)(end - beg), 1.0f);
  const ushort2 rr = *(const ushort2*)(Acat + (size_t)node * 512 + 384 + c2);
  const float2 b = *(const float2*)&bl2[c2];
  const float vx = fmaf(ax, inv, b.x) + bf2f(rr.x);
  const float vy = fmaf(ay, inv, b.y) + bf2f(rr.y);
  float ss = vx * vx + vy * vy;
#pragma unroll
  for (int off = 32; off > 0; off >>= 1) ss += __shfl_xor(ss, off);
  const float rn = 1.0f / fmaxf(sqrtf(ss), 1e-12f);
  *(float2*)&out[(size_t)node * 128 + c2] = make_float2(vx * rn, vy * rn);
}

// ---------------------------------------------------------------------------
extern "C" void kernel_launch(void* const* d_in, const int* in_sizes, int n_in,
                              void* d_out, int out_size, void* d_ws, size_t ws_size,
                              hipStream_t stream) {
  const float* x      = (const float*)d_in[0];
  const int*   ei     = (const int*)d_in[1];
  const float* W_pre  = (const float*)d_in[2];
  const float* b_pre  = (const float*)d_in[3];
  const float* W_pre2 = (const float*)d_in[4];
  const float* b_pre2 = (const float*)d_in[5];
  const float* Wl1    = (const float*)d_in[6];
  const float* bl1    = (const float*)d_in[7];
  const float* Wr1    = (const float*)d_in[8];
  const float* Wl2    = (const float*)d_in[9];
  const float* bl2    = (const float*)d_in[10];
  const float* Wr2    = (const float*)d_in[11];
  float* out = (float*)d_out;

  const int M = in_sizes[0] / 512;  // 50000
  const int E = in_sizes[1] / 2;    // 800000
  const int* src = ei;
  const int* dst = ei + E;

  // workspace: Acat bf16[M*512] | H3 bf16[M*256] | Wc[256*512] | Bc1[256*512]
  //   | Bc2[256*256] | bc f32[256] | rowptr[M+1] | cnt[M] | bsum | boff |
  //   eidx ushort[E]   (~80 MB)
  char* p = (char*)d_ws;
  unsigned short* Acat = (unsigned short*)p; p += (size_t)M * 512 * 2;
  unsigned short* H3   = (unsigned short*)p; p += (size_t)M * 256 * 2;
  unsigned short* Wc   = (unsigned short*)p; p += 256 * 512 * 2;
  unsigned short* Bc1  = (unsigned short*)p; p += 256 * 512 * 2;
  unsigned short* Bc2  = (unsigned short*)p; p += 256 * 256 * 2;
  float* bc   = (float*)p; p += 256 * 4;
  int* rowptr = (int*)p;   p += (size_t)(M + 1) * 4;
  int* cnt    = (int*)p;   p += (size_t)M * 4;
  int* bsum   = (int*)p;   p += 256 * 4;
  int* boff   = (int*)p;   p += 256 * 4;
  unsigned short* eidx = (unsigned short*)p;

  const int eblk = (E + 255) / 256;
  const int nb   = (M + 255) / 256;         // 196
  const int nwg  = ((M + 127) / 128) * 2;   // 782 (1-D grid, XCD-chunked)
  const int nblk = (M + 3) / 4;

  // CSR build
  zero_int_kernel<<<256, 256, 0, stream>>>(cnt, M);
  count_kernel<<<eblk, 256, 0, stream>>>(dst, cnt, E);
  scan_pass1<<<nb, 256, 0, stream>>>(cnt, bsum, M);
  scan_pass2<<<1, 256, 0, stream>>>(bsum, boff, rowptr, nb, M, E);
  scan_pass3<<<nb, 256, 0, stream>>>(cnt, boff, rowptr, M);
  fill_kernel<<<eblk, 256, 0, stream>>>(src, dst, rowptr, cnt, eidx, E);

  // fused weight prep
  prep_kernel<<<1025, 256, 0, stream>>>(W_pre, W_pre2, b_pre, b_pre2,
                                        Wl1, Wr1, Wl2, Wr2, Wc, bc, Bc1, Bc2);

  // H2 = x @ Wc.T + bc  -> Acat cols 256..511 (fp32 A fused conversion)
  mfma_gemm<512, 512, 512, 256, true, false, true>
      <<<nwg, 256, 0, stream>>>(x, Wc, bc, Acat, M, nwg);
  // mean1 -> Acat cols 0..255
  gather_mean256_kernel<<<nblk, 256, 0, stream>>>(Acat, rowptr, eidx, M);
  // H3 = relu(Acat @ Bc1.T + bl1)
  mfma_gemm<512, 512, 256, 0, true, true, false>
      <<<nwg, 256, 0, stream>>>(Acat, Bc1, bl1, H3, M, nwg);
  // TR = H3 @ Bc2.T -> Acat cols 256..511 (H2 dead)
  mfma_gemm<256, 256, 512, 256, false, false, false>
      <<<nwg, 256, 0, stream>>>(H3, Bc2, nullptr, Acat, M, nwg);
  // out = l2norm(mean(T) + bl2 + R)
  gather_finalize_kernel<<<nblk, 256, 0, stream>>>(Acat, rowptr, eidx, bl2, out, M);
}